// Round 12
// baseline (27295.566 us; speedup 1.0000x reference)
//
#include <hip/hip_runtime.h>
#include <hip/hip_bf16.h>
#include <cstddef>

#define NN 32768
#define BM 64
#define BN 64
#define BK 32

typedef float f32x4 __attribute__((ext_vector_type(4)));
typedef short short8 __attribute__((ext_vector_type(8)));

__device__ inline unsigned short f2bf(float f) {
    unsigned u = __builtin_bit_cast(unsigned, f);
    unsigned r = (u + 0x7FFFu + ((u >> 16) & 1u)) >> 16;
    return (unsigned short)r;
}
__device__ inline float sigmoid_f(float x) {
    float e = __expf(-x);
    return __builtin_amdgcn_rcpf(1.f + e);
}
__device__ inline float tanh_f(float x) {
    float e = __expf(-2.f * x);
    return 2.f * __builtin_amdgcn_rcpf(1.f + e) - 1.f;
}

// Unit-major gate permutation: permuted position p = w*64 + u'*4 + nt
// (w = wave, u' = unit-in-wave, nt = gate i/f/g/o) -> original gate row
// nt*128 + w*16 + u'. Scan reads the 4 gates of a unit as one float4.
__device__ inline int permrow(int p) {
    return (p & 3) * 128 + ((p >> 6) << 4) + ((p >> 2) & 15);
}

// Generic fp32 GEMM: C[M,N] = concat(A1[idx],A2[idx]) @ W[N,K].T + b1 (+ b2)
// permW: output column gc uses W row permrow(gc) and bias permrow(gc).
__global__ __launch_bounds__(256) void gemm_cat(
    const float* __restrict__ A1, const int* __restrict__ idx1,
    const float* __restrict__ A2, const int* __restrict__ idx2, int istr,
    int K1, int K2,
    const float* __restrict__ W, const float* __restrict__ b1,
    const float* __restrict__ b2, int permW,
    float* __restrict__ C, int M, int N)
{
    const int K = K1 + K2;
    __shared__ __align__(16) float As[BK][BM + 4];  // [k][m]
    __shared__ __align__(16) float Ws[BK][BN + 4];  // [k][n]
    const int tid = threadIdx.x;
    const int m0 = blockIdx.x * BM;
    const int n0 = blockIdx.y * BN;
    const int tx = tid & 15;
    const int ty = tid >> 4;
    float acc[4][4] = {};

    for (int k0 = 0; k0 < K; k0 += BK) {
        #pragma unroll
        for (int p = 0; p < 2; ++p) {
            int q = tid + p * 256;
            int row = q >> 3;
            int kq = (q & 7) * 4;
            int gk = k0 + kq;
            int grow = m0 + row;
            const float* src;
            if (gk < K1) {
                int r = idx1 ? idx1[grow * istr] : grow;
                src = A1 + (size_t)r * K1 + gk;
            } else {
                int r = idx2 ? idx2[grow * istr] : grow;
                src = A2 + (size_t)r * K2 + (gk - K1);
            }
            float4 v = *(const float4*)src;
            As[kq + 0][row] = v.x; As[kq + 1][row] = v.y;
            As[kq + 2][row] = v.z; As[kq + 3][row] = v.w;
        }
        #pragma unroll
        for (int p = 0; p < 2; ++p) {
            int q = tid + p * 256;
            int row = q >> 3;
            int kq = (q & 7) * 4;
            int wrow = n0 + row;
            if (permW) wrow = permrow(wrow);
            const float* src = W + (size_t)wrow * K + (k0 + kq);
            float4 v = *(const float4*)src;
            Ws[kq + 0][row] = v.x; Ws[kq + 1][row] = v.y;
            Ws[kq + 2][row] = v.z; Ws[kq + 3][row] = v.w;
        }
        __syncthreads();
        #pragma unroll
        for (int kk = 0; kk < BK; ++kk) {
            float4 a = *(const float4*)&As[kk][ty * 4];
            float4 b = *(const float4*)&Ws[kk][tx * 4];
            float av[4] = {a.x, a.y, a.z, a.w};
            float bv[4] = {b.x, b.y, b.z, b.w};
            #pragma unroll
            for (int i = 0; i < 4; ++i)
                #pragma unroll
                for (int jj = 0; jj < 4; ++jj)
                    acc[i][jj] += av[i] * bv[jj];
        }
        __syncthreads();
    }
    #pragma unroll
    for (int i = 0; i < 4; ++i) {
        int gr = m0 + ty * 4 + i;
        #pragma unroll
        for (int jj = 0; jj < 4; ++jj) {
            int gc = n0 + tx * 4 + jj;
            int bi = permW ? permrow(gc) : gc;
            float bias = b1 ? b1[bi] : 0.f;
            if (b2) bias += b2[bi];
            C[(size_t)gr * N + gc] = acc[i][jj] + bias;
        }
    }
}

// Barrier draining only LDS ops (not hs global stores / xg prefetch loads).
#define LDS_BARRIER() asm volatile("s_waitcnt lgkmcnt(0)\n\ts_barrier" ::: "memory")

// MFMA LSTM scan -- R11 structure + gate-dependency-ordered MFMA issue.
// R11 counters: MfmaUtil/CU 53% + VALUBusy/CU 51% (partial overlap),
// 960 cyc/step = MFMA issue ~620/SIMD + exposed act tail ~200 + sync.
// All 4 gate chains finished together (kt-outer round-robin), leaving the
// whole act->c->tanh(c)->h chain exposed after the last MFMA. This round:
// issue i,f,g chains (12 MFMAs) first, then o's chain (4 MFMAs), then
// acts(i,f,g)+c+tanh(c) -- which the scheduler can overlap with o's
// drain -- and sigmoid(o) last (h = ov*th needs o only at the end).
// Arithmetic is op-for-op identical => absmax must stay 0.001953125.
// Register-file lesson (R9/R10): persistent weights MUST be MFMA operands
// (native AGPR reads); VALU consumers pay v_accvgpr_read copies.
__global__ __launch_bounds__(512)
__attribute__((amdgpu_waves_per_eu(2, 2)))
void lstm_scan(const float* __restrict__ xg,    // [T, 512] unit-major perm
               const float* __restrict__ Whh,   // [512, 128] fp32 original
               float* __restrict__ hs,          // [T, 128] fp32
               int T)
{
    __shared__ __align__(16) unsigned short hbuf[2][128];  // h in bf16
    const int tid  = threadIdx.x;
    const int w    = tid >> 6;
    const int lane = tid & 63;
    const int m    = lane & 15;   // unit-in-wave (D column)
    const int grp  = lane >> 4;   // k-group for A/B frags

    // B fragments: gate tile nt, k-tile kt:
    // B[k = kt*32+grp*8+j][col = m] = Whh[nt*128 + w*16 + m][kt*32+grp*8+j]
    short8 wfrag[4][4];
    #pragma unroll
    for (int nt = 0; nt < 4; ++nt)
        #pragma unroll
        for (int kt = 0; kt < 4; ++kt) {
            const float* src = Whh + (size_t)(nt * 128 + w * 16 + m) * 128
                                   + kt * 32 + grp * 8;
            f32x4 v0 = *(const f32x4*)src;
            f32x4 v1 = *(const f32x4*)(src + 4);
            short8 s;
            s[0] = (short)f2bf(v0[0]); s[1] = (short)f2bf(v0[1]);
            s[2] = (short)f2bf(v0[2]); s[3] = (short)f2bf(v0[3]);
            s[4] = (short)f2bf(v1[0]); s[5] = (short)f2bf(v1[1]);
            s[6] = (short)f2bf(v1[2]); s[7] = (short)f2bf(v1[3]);
            wfrag[nt][kt] = s;
        }

    if (tid < 128) { hbuf[0][tid] = 0; hbuf[1][tid] = 0; }

    // xg: float4 {i,f,g,o} of unit w*16+m at permuted pos w*64 + m*4
    const int xoff = w * 64 + m * 4;
    f32x4 xcA = *(const f32x4*)(xg + xoff);
    f32x4 xcB = *(const f32x4*)(xg + 512 + xoff);
    const float* xpre = xg + 2 * 512 + xoff;   // prefetch base (step t+2)
    float* hsp = hs + w * 16 + m;              // store base (grp==0 lanes)
    float c = 0.f;
    f32x4 acc[4];
    #pragma unroll
    for (int nt = 0; nt < 4; ++nt) acc[nt] = (f32x4){0.f, 0.f, 0.f, 0.f};
    __syncthreads();

    for (int t = 0; t < T; t += 2) {
        #pragma unroll
        for (int half = 0; half < 2; ++half) {
            // A fragments: h replicated; lane reads h[kt*32+grp*8 .. +7]
            const unsigned short* hb = hbuf[half];
            short8 hfrag[4];
            #pragma unroll
            for (int kt = 0; kt < 4; ++kt)
                hfrag[kt] = *(const short8*)&hb[kt * 32 + grp * 8];

            // C-init: only element 0 (the D element we read) gets xg
            #pragma unroll
            for (int nt = 0; nt < 4; ++nt)
                acc[nt][0] = half ? xcB[nt] : xcA[nt];

            // prefetch xg for t+2 / t+3 into the slot just consumed
            if (half == 0) { if (t + 2 < T) xcA = *(const f32x4*)xpre; }
            else           { if (t + 3 < T) xcB = *(const f32x4*)(xpre + 512); }

            // i,f,g chains first (kt-outer, 3-way round-robin ILP)
            #pragma unroll
            for (int kt = 0; kt < 4; ++kt)
                #pragma unroll
                for (int nt = 0; nt < 3; ++nt)
                    acc[nt] = __builtin_amdgcn_mfma_f32_16x16x32_bf16(
                        hfrag[kt], wfrag[nt][kt], acc[nt], 0, 0, 0);
            // o chain last -- drains while i,f,g acts + c-chain run
            #pragma unroll
            for (int kt = 0; kt < 4; ++kt)
                acc[3] = __builtin_amdgcn_mfma_f32_16x16x32_bf16(
                    hfrag[kt], wfrag[3][kt], acc[3], 0, 0, 0);

            // acts for i,f,g + c-chain (independent of o's MFMAs)
            float iv = sigmoid_f(acc[0][0]);
            float fv = sigmoid_f(acc[1][0]);
            float gv = tanh_f   (acc[2][0]);
            c = fv * c + iv * gv;
            float th = tanh_f(c);
            // o needed only here, at the very end
            float ov = sigmoid_f(acc[3][0]);
            float h = ov * th;

            if (grp == 0) {   // 16 lanes write this wave's 16 units
                unsigned hp;
                asm("v_cvt_pk_bf16_f32 %0, %1, %1" : "=v"(hp) : "v"(h));
                hbuf[half ^ 1][w * 16 + m] = (unsigned short)hp;
                hsp[half * 128] = h;
            }
            LDS_BARRIER();
        }
        xpre += 1024;
        hsp  += 256;
    }
}

extern "C" void kernel_launch(void* const* d_in, const int* in_sizes, int n_in,
                              void* d_out, int out_size, void* d_ws, size_t ws_size,
                              hipStream_t stream) {
    const float* inputs = (const float*)d_in[0];
    const int*   edges  = (const int*)d_in[1];     // [N,2] int32
    const float* in_W   = (const float*)d_in[2];   // [128,128]
    const float* in_b   = (const float*)d_in[3];   // [128]
    const float* out_W  = (const float*)d_in[4];   // [128,128]
    const float* out_b  = (const float*)d_in[5];   // [128]
    const float* edge_W = (const float*)d_in[6];   // [2,128,256]
    const float* edge_b = (const float*)d_in[7];   // [2,128]
    const float* Wih    = (const float*)d_in[8];   // [2,512,256]
    const float* Whh    = (const float*)d_in[9];   // [2,512,128]
    const float* bih    = (const float*)d_in[10];  // [2,512]
    const float* bhh    = (const float*)d_in[11];  // [2,512]
    float* out = (float*)d_out;

    float* ws = (float*)d_ws;
    float* nodesA = ws;                          // 32768*128
    float* nodesB = nodesA + (size_t)NN * 128;   // 32768*128
    float* edge_h = nodesB + (size_t)NN * 128;   // 32768*128
    float* xgbuf  = edge_h + (size_t)NN * 128;   // 32768*512

    dim3 blk(256);
    dim3 g128(NN / BM, 128 / BN);
    dim3 g512(NN / BM, 512 / BN);

    // nodes = inputs @ in_W.T + in_b
    gemm_cat<<<g128, blk, 0, stream>>>(inputs, nullptr, nullptr, nullptr, 1,
                                       128, 0, in_W, in_b, nullptr, 0,
                                       nodesA, NN, 128);

    const float* cur = nodesA;
    float* nxt = nodesB;
    for (int r = 0; r < 2; ++r) {
        // edge_h = concat(nodes[src], nodes[dst]) @ edge_W[r].T + edge_b[r]
        gemm_cat<<<g128, blk, 0, stream>>>(cur, edges + 0, cur, edges + 1, 2,
                                           128, 128,
                                           edge_W + (size_t)r * 128 * 256,
                                           edge_b + (size_t)r * 128, nullptr, 0,
                                           edge_h, NN, 128);
        // xg = concat(inputs, edge_h) @ Wih[r].T + bih[r] + bhh[r], PERMUTED
        gemm_cat<<<g512, blk, 0, stream>>>(inputs, nullptr, edge_h, nullptr, 1,
                                           128, 128,
                                           Wih + (size_t)r * 512 * 256,
                                           bih + (size_t)r * 512,
                                           bhh + (size_t)r * 512, 1,
                                           xgbuf, NN, 512);
        // sequential LSTM scan (MFMA, gate-dependency-ordered)
        lstm_scan<<<1, 512, 0, stream>>>(xgbuf, Whh + (size_t)r * 512 * 128,
                                         nxt, NN);
        const float* tmp = cur;
        cur = nxt;
        nxt = (float*)tmp;
    }

    // out = nodes @ out_W.T + out_b
    gemm_cat<<<g128, blk, 0, stream>>>(cur, nullptr, nullptr, nullptr, 1,
                                       128, 0, out_W, out_b, nullptr, 0,
                                       out, NN, 128);
}

// Round 13
// 26572.382 us; speedup vs baseline: 1.0272x; 1.0272x over previous
//
#include <hip/hip_runtime.h>
#include <hip/hip_bf16.h>
#include <cstddef>

#define NN 32768
#define BM 64
#define BN 64
#define BK 32

typedef float f32x4 __attribute__((ext_vector_type(4)));
typedef short short8 __attribute__((ext_vector_type(8)));

__device__ inline unsigned short f2bf(float f) {
    unsigned u = __builtin_bit_cast(unsigned, f);
    unsigned r = (u + 0x7FFFu + ((u >> 16) & 1u)) >> 16;
    return (unsigned short)r;
}
__device__ inline float sigmoid_f(float x) {
    float e = __expf(-x);
    return __builtin_amdgcn_rcpf(1.f + e);
}
__device__ inline float tanh_f(float x) {
    float e = __expf(-2.f * x);
    return 2.f * __builtin_amdgcn_rcpf(1.f + e) - 1.f;
}

// Unit-major gate permutation: permuted position p = w*64 + u'*4 + nt
// (w = wave, u' = unit-in-wave, nt = gate i/f/g/o) -> original gate row
// nt*128 + w*16 + u'. Scan reads the 4 gates of a unit as one float4.
__device__ inline int permrow(int p) {
    return (p & 3) * 128 + ((p >> 6) << 4) + ((p >> 2) & 15);
}

// Generic fp32 GEMM: C[M,N] = concat(A1[idx],A2[idx]) @ W[N,K].T + b1 (+ b2)
// permW: output column gc uses W row permrow(gc) and bias permrow(gc).
__global__ __launch_bounds__(256) void gemm_cat(
    const float* __restrict__ A1, const int* __restrict__ idx1,
    const float* __restrict__ A2, const int* __restrict__ idx2, int istr,
    int K1, int K2,
    const float* __restrict__ W, const float* __restrict__ b1,
    const float* __restrict__ b2, int permW,
    float* __restrict__ C, int M, int N)
{
    const int K = K1 + K2;
    __shared__ __align__(16) float As[BK][BM + 4];  // [k][m]
    __shared__ __align__(16) float Ws[BK][BN + 4];  // [k][n]
    const int tid = threadIdx.x;
    const int m0 = blockIdx.x * BM;
    const int n0 = blockIdx.y * BN;
    const int tx = tid & 15;
    const int ty = tid >> 4;
    float acc[4][4] = {};

    for (int k0 = 0; k0 < K; k0 += BK) {
        #pragma unroll
        for (int p = 0; p < 2; ++p) {
            int q = tid + p * 256;
            int row = q >> 3;
            int kq = (q & 7) * 4;
            int gk = k0 + kq;
            int grow = m0 + row;
            const float* src;
            if (gk < K1) {
                int r = idx1 ? idx1[grow * istr] : grow;
                src = A1 + (size_t)r * K1 + gk;
            } else {
                int r = idx2 ? idx2[grow * istr] : grow;
                src = A2 + (size_t)r * K2 + (gk - K1);
            }
            float4 v = *(const float4*)src;
            As[kq + 0][row] = v.x; As[kq + 1][row] = v.y;
            As[kq + 2][row] = v.z; As[kq + 3][row] = v.w;
        }
        #pragma unroll
        for (int p = 0; p < 2; ++p) {
            int q = tid + p * 256;
            int row = q >> 3;
            int kq = (q & 7) * 4;
            int wrow = n0 + row;
            if (permW) wrow = permrow(wrow);
            const float* src = W + (size_t)wrow * K + (k0 + kq);
            float4 v = *(const float4*)src;
            Ws[kq + 0][row] = v.x; Ws[kq + 1][row] = v.y;
            Ws[kq + 2][row] = v.z; Ws[kq + 3][row] = v.w;
        }
        __syncthreads();
        #pragma unroll
        for (int kk = 0; kk < BK; ++kk) {
            float4 a = *(const float4*)&As[kk][ty * 4];
            float4 b = *(const float4*)&Ws[kk][tx * 4];
            float av[4] = {a.x, a.y, a.z, a.w};
            float bv[4] = {b.x, b.y, b.z, b.w};
            #pragma unroll
            for (int i = 0; i < 4; ++i)
                #pragma unroll
                for (int jj = 0; jj < 4; ++jj)
                    acc[i][jj] += av[i] * bv[jj];
        }
        __syncthreads();
    }
    #pragma unroll
    for (int i = 0; i < 4; ++i) {
        int gr = m0 + ty * 4 + i;
        #pragma unroll
        for (int jj = 0; jj < 4; ++jj) {
            int gc = n0 + tx * 4 + jj;
            int bi = permW ? permrow(gc) : gc;
            float bias = b1 ? b1[bi] : 0.f;
            if (b2) bias += b2[bi];
            C[(size_t)gr * N + gc] = acc[i][jj] + bias;
        }
    }
}

// Barrier draining only LDS ops (not hs global stores / xg prefetch loads).
#define LDS_BARRIER() asm volatile("s_waitcnt lgkmcnt(0)\n\ts_barrier" ::: "memory")

// MFMA LSTM scan -- FINAL (R11 = best measured: 13.1 ms/scan, 26.6 ms total).
// Structure: D = A(h replicated) x B(Whh^T) via mfma_f32_16x16x32_bf16;
// 8 waves, wave w owns units w*16..+15; lane (grp, m) reads all 4 gates of
// unit w*16+m from acc[0..3][0]; interleaved kt-outer MFMA order (4-way ILP,
// R12 showed splitting the o-chain regresses); unit-major xg (one float4 +
// one prefetch load/step); only acc[nt][0] re-initialized from xg (other
// elements/replicas carry a bounded never-read random walk); 2-step unroll
// with static hbuf ping-pong; v_cvt_pk_bf16_f32 h-pack; lgkm-only barrier.
// Register-file lesson (R9/R10): persistent weights MUST be MFMA operands
// (native AGPR reads); VALU consumers pay v_accvgpr_read copies.
// Step floor (R11 counters): MFMA issue ~620 cyc/SIMD (structural 16x
// matvec-on-matrix-engine tax) + partially-overlapped ds_read/act/barrier.
__global__ __launch_bounds__(512)
__attribute__((amdgpu_waves_per_eu(2, 2)))
void lstm_scan(const float* __restrict__ xg,    // [T, 512] unit-major perm
               const float* __restrict__ Whh,   // [512, 128] fp32 original
               float* __restrict__ hs,          // [T, 128] fp32
               int T)
{
    __shared__ __align__(16) unsigned short hbuf[2][128];  // h in bf16
    const int tid  = threadIdx.x;
    const int w    = tid >> 6;
    const int lane = tid & 63;
    const int m    = lane & 15;   // unit-in-wave (D column)
    const int grp  = lane >> 4;   // k-group for A/B frags

    // B fragments: gate tile nt, k-tile kt:
    // B[k = kt*32+grp*8+j][col = m] = Whh[nt*128 + w*16 + m][kt*32+grp*8+j]
    short8 wfrag[4][4];
    #pragma unroll
    for (int nt = 0; nt < 4; ++nt)
        #pragma unroll
        for (int kt = 0; kt < 4; ++kt) {
            const float* src = Whh + (size_t)(nt * 128 + w * 16 + m) * 128
                                   + kt * 32 + grp * 8;
            f32x4 v0 = *(const f32x4*)src;
            f32x4 v1 = *(const f32x4*)(src + 4);
            short8 s;
            s[0] = (short)f2bf(v0[0]); s[1] = (short)f2bf(v0[1]);
            s[2] = (short)f2bf(v0[2]); s[3] = (short)f2bf(v0[3]);
            s[4] = (short)f2bf(v1[0]); s[5] = (short)f2bf(v1[1]);
            s[6] = (short)f2bf(v1[2]); s[7] = (short)f2bf(v1[3]);
            wfrag[nt][kt] = s;
        }

    if (tid < 128) { hbuf[0][tid] = 0; hbuf[1][tid] = 0; }

    // xg: float4 {i,f,g,o} of unit w*16+m at permuted pos w*64 + m*4
    const int xoff = w * 64 + m * 4;
    f32x4 xcA = *(const f32x4*)(xg + xoff);
    f32x4 xcB = *(const f32x4*)(xg + 512 + xoff);
    const float* xpre = xg + 2 * 512 + xoff;   // prefetch base (step t+2)
    float* hsp = hs + w * 16 + m;              // store base (grp==0 lanes)
    float c = 0.f;
    f32x4 acc[4];
    #pragma unroll
    for (int nt = 0; nt < 4; ++nt) acc[nt] = (f32x4){0.f, 0.f, 0.f, 0.f};
    __syncthreads();

    for (int t = 0; t < T; t += 2) {
        #pragma unroll
        for (int half = 0; half < 2; ++half) {
            // A fragments: h replicated; lane reads h[kt*32+grp*8 .. +7]
            const unsigned short* hb = hbuf[half];
            short8 hfrag[4];
            #pragma unroll
            for (int kt = 0; kt < 4; ++kt)
                hfrag[kt] = *(const short8*)&hb[kt * 32 + grp * 8];

            // C-init: only element 0 (the D element we read) gets xg
            #pragma unroll
            for (int nt = 0; nt < 4; ++nt)
                acc[nt][0] = half ? xcB[nt] : xcA[nt];

            // prefetch xg for t+2 / t+3 into the slot just consumed
            if (half == 0) { if (t + 2 < T) xcA = *(const f32x4*)xpre; }
            else           { if (t + 3 < T) xcB = *(const f32x4*)(xpre + 512); }

            #pragma unroll
            for (int kt = 0; kt < 4; ++kt)   // kt outer: 4 interleaved chains
                #pragma unroll
                for (int nt = 0; nt < 4; ++nt)
                    acc[nt] = __builtin_amdgcn_mfma_f32_16x16x32_bf16(
                        hfrag[kt], wfrag[nt][kt], acc[nt], 0, 0, 0);

            // all 4 gates of unit w*16+m, static indices, ILP-4
            float iv = sigmoid_f(acc[0][0]);
            float fv = sigmoid_f(acc[1][0]);
            float gv = tanh_f   (acc[2][0]);
            float ov = sigmoid_f(acc[3][0]);
            c = fv * c + iv * gv;
            float h = ov * tanh_f(c);

            if (grp == 0) {   // 16 lanes write this wave's 16 units
                unsigned hp;
                asm("v_cvt_pk_bf16_f32 %0, %1, %1" : "=v"(hp) : "v"(h));
                hbuf[half ^ 1][w * 16 + m] = (unsigned short)hp;
                hsp[half * 128] = h;
            }
            LDS_BARRIER();
        }
        xpre += 1024;
        hsp  += 256;
    }
}

extern "C" void kernel_launch(void* const* d_in, const int* in_sizes, int n_in,
                              void* d_out, int out_size, void* d_ws, size_t ws_size,
                              hipStream_t stream) {
    const float* inputs = (const float*)d_in[0];
    const int*   edges  = (const int*)d_in[1];     // [N,2] int32
    const float* in_W   = (const float*)d_in[2];   // [128,128]
    const float* in_b   = (const float*)d_in[3];   // [128]
    const float* out_W  = (const float*)d_in[4];   // [128,128]
    const float* out_b  = (const float*)d_in[5];   // [128]
    const float* edge_W = (const float*)d_in[6];   // [2,128,256]
    const float* edge_b = (const float*)d_in[7];   // [2,128]
    const float* Wih    = (const float*)d_in[8];   // [2,512,256]
    const float* Whh    = (const float*)d_in[9];   // [2,512,128]
    const float* bih    = (const float*)d_in[10];  // [2,512]
    const float* bhh    = (const float*)d_in[11];  // [2,512]
    float* out = (float*)d_out;

    float* ws = (float*)d_ws;
    float* nodesA = ws;                          // 32768*128
    float* nodesB = nodesA + (size_t)NN * 128;   // 32768*128
    float* edge_h = nodesB + (size_t)NN * 128;   // 32768*128
    float* xgbuf  = edge_h + (size_t)NN * 128;   // 32768*512

    dim3 blk(256);
    dim3 g128(NN / BM, 128 / BN);
    dim3 g512(NN / BM, 512 / BN);

    // nodes = inputs @ in_W.T + in_b
    gemm_cat<<<g128, blk, 0, stream>>>(inputs, nullptr, nullptr, nullptr, 1,
                                       128, 0, in_W, in_b, nullptr, 0,
                                       nodesA, NN, 128);

    const float* cur = nodesA;
    float* nxt = nodesB;
    for (int r = 0; r < 2; ++r) {
        // edge_h = concat(nodes[src], nodes[dst]) @ edge_W[r].T + edge_b[r]
        gemm_cat<<<g128, blk, 0, stream>>>(cur, edges + 0, cur, edges + 1, 2,
                                           128, 128,
                                           edge_W + (size_t)r * 128 * 256,
                                           edge_b + (size_t)r * 128, nullptr, 0,
                                           edge_h, NN, 128);
        // xg = concat(inputs, edge_h) @ Wih[r].T + bih[r] + bhh[r], PERMUTED
        gemm_cat<<<g512, blk, 0, stream>>>(inputs, nullptr, edge_h, nullptr, 1,
                                           128, 128,
                                           Wih + (size_t)r * 512 * 256,
                                           bih + (size_t)r * 512,
                                           bhh + (size_t)r * 512, 1,
                                           xgbuf, NN, 512);
        // sequential LSTM scan (MFMA, R11 final)
        lstm_scan<<<1, 512, 0, stream>>>(xgbuf, Whh + (size_t)r * 512 * 128,
                                         nxt, NN);
        const float* tmp = cur;
        cur = nxt;
        nxt = (float*)tmp;
    }

    // out = nodes @ out_W.T + out_b
    gemm_cat<<<g128, blk, 0, stream>>>(cur, nullptr, nullptr, nullptr, 1,
                                       128, 0, out_W, out_b, nullptr, 0,
                                       out, NN, 128);
}